// Round 10
// baseline (509.497 us; speedup 1.0000x reference)
//
#include <hip/hip_runtime.h>

// ---------------- types / helpers ----------------
typedef __bf16 bf16x8 __attribute__((ext_vector_type(8)));
typedef float f32x4 __attribute__((ext_vector_type(4)));
typedef unsigned short u16x8 __attribute__((ext_vector_type(8)));

__device__ __forceinline__ unsigned short f2bf(float f) {
  union { float f; unsigned int u; } v; v.f = f;
  unsigned int r = v.u + 0x7fffu + ((v.u >> 16) & 1u);  // RNE
  return (unsigned short)(r >> 16);
}

__device__ __forceinline__ void async16(const unsigned short* g, unsigned short* l) {
  __builtin_amdgcn_global_load_lds(
      (const __attribute__((address_space(1))) unsigned int*)g,
      (__attribute__((address_space(3))) unsigned int*)l, 16, 0, 0);
}

// ---------------- fused converts: all weights + memory + bias concat, ONE launch ------
__global__ void cvt_all(const float* __restrict__ q_w, const float* __restrict__ k_w,
                        const float* __restrict__ v_w, const float* __restrict__ o_w,
                        const float* __restrict__ f1w, const float* __restrict__ f2w,
                        const float* __restrict__ mem,
                        const float* __restrict__ q_b, const float* __restrict__ k_b,
                        const float* __restrict__ v_b,
                        unsigned short* __restrict__ WQ, unsigned short* __restrict__ WK,
                        unsigned short* __restrict__ WV, unsigned short* __restrict__ WO,
                        unsigned short* __restrict__ WF1, unsigned short* __restrict__ WF2,
                        unsigned short* __restrict__ MEMB, float* __restrict__ QKVB) {
  const int bid = blockIdx.x;
  const float* src; unsigned short* dst; float scale = 1.f; int base;
  if (bid < 1024)       { src = q_w; dst = WQ;  scale = 0.125f; base = 0; }
  else if (bid < 2048)  { src = k_w; dst = WK;  base = 1024; }
  else if (bid < 3072)  { src = v_w; dst = WV;  base = 2048; }
  else if (bid < 4096)  { src = o_w; dst = WO;  base = 3072; }
  else if (bid < 8192)  { src = f1w; dst = WF1; base = 4096; }
  else if (bid < 12288) { src = f2w; dst = WF2; base = 8192; }
  else if (bid < 13312) { src = mem; dst = MEMB; base = 12288; }
  else {  // bias concat (12 blocks, 3072 elems), q-bias pre-scaled
    const int i = (bid - 13312) * 256 + threadIdx.x;
    QKVB[i] = (i < 1024) ? q_b[i] * 0.125f : (i < 2048 ? k_b[i - 1024] : v_b[i - 2048]);
    return;
  }
  const int i = (bid - base) * 256 + threadIdx.x;
  float4 v = ((const float4*)src)[i];
  ushort4 o;
  o.x = f2bf(v.x * scale); o.y = f2bf(v.y * scale);
  o.z = f2bf(v.z * scale); o.w = f2bf(v.w * scale);
  ((ushort4*)dst)[i] = o;
}

// ---------------- LayerNorm (per 1024-row) -> bf16 ----------------
template <int PREFILL>
__global__ __launch_bounds__(256) void ln_bf16(
    const float* __restrict__ src, unsigned short* __restrict__ dst,
    const float* __restrict__ g, const float* __restrict__ be,
    const float* __restrict__ fbias, float* __restrict__ dout) {
  const int row = blockIdx.x, tid = threadIdx.x;
  const float4 v = ((const float4*)(src + (size_t)row * 1024))[tid];
  if (PREFILL) {
    const float4 fb = ((const float4*)fbias)[tid];
    float4 r;
    r.x = v.x + fb.x; r.y = v.y + fb.y; r.z = v.z + fb.z; r.w = v.w + fb.w;
    ((float4*)(dout + (size_t)row * 1024))[tid] = r;
  }
  float s = v.x + v.y + v.z + v.w;
  float qq = v.x * v.x + v.y * v.y + v.z * v.z + v.w * v.w;
#pragma unroll
  for (int off = 32; off; off >>= 1) { s += __shfl_xor(s, off); qq += __shfl_xor(qq, off); }
  __shared__ float ps[4], pq[4];
  const int w = tid >> 6, lane = tid & 63;
  if (lane == 0) { ps[w] = s; pq[w] = qq; }
  __syncthreads();
  if (tid == 0) { ps[0] = ps[0] + ps[1] + ps[2] + ps[3]; pq[0] = pq[0] + pq[1] + pq[2] + pq[3]; }
  __syncthreads();
  const float mu = ps[0] * (1.f / 1024.f);
  const float var = pq[0] * (1.f / 1024.f) - mu * mu;
  const float rs = rsqrtf(var + 1e-5f);
  const float4 gv = ((const float4*)g)[tid];
  const float4 bv = ((const float4*)be)[tid];
  ushort4 o;
  o.x = f2bf((v.x - mu) * rs * gv.x + bv.x);
  o.y = f2bf((v.y - mu) * rs * gv.y + bv.y);
  o.z = f2bf((v.z - mu) * rs * gv.z + bv.z);
  o.w = f2bf((v.w - mu) * rs * gv.w + bv.w);
  ((ushort4*)(dst + (size_t)row * 1024))[tid] = o;
}

// ---------------- GEMM: C[M,N] = A[M,K] @ B[N,K]^T (+ bias), m97-style ----------------
// SESSION LEDGER (r1-9): deep-pipeline engines (2-phase, +T2 swizzle, depth-3 ring)
// all parity-or-worse — latency-bound at 1 block/CU. This 256-thr/small-LDS kernel
// keeps 3-6 blocks/CU and m114 implicit wave overlap pipelines for free. Measured:
// fc1@1536 (6 blk/CU) ~20us faster than @768-class; fc2 split-K 4 regressed via
// +47MB atomic HBM (TLP must be byte-free).
// ROUND 10: BNT template (128 or 64 N-cols per tile). BNT=64 doubles tile count ->
// doubles blocks/CU with IDENTICAL HBM bytes (L3 absorbs the extra panel re-reads).
// fc2: 48mx16nx2kz = 1536 = 6 blk/CU. outproj: 48x16 = 768 = 3 blk/CU (was 1.5).
// (256,4): reg cap 128 — no spill ((256,8) forced VGPR=32 -> scratch catastrophe,
// round 2); floor-guarantee only, does NOT cap occupancy.
#define KOFF 6291456ull
#define VOFF 13631488ull
template <int EPI, int BNT>
__global__ __launch_bounds__(256, 4) void gemm_bt(
    const unsigned short* __restrict__ A, const unsigned short* __restrict__ Bw,
    const float* __restrict__ bias, const float* __restrict__ resid,
    void* __restrict__ Cout, int M, int N, int K, int lda, int ldb, int NBN, int WM) {
  constexpr int NJ = BNT / 32;  // B-frags per wave; wave covers 16*NJ cols
  __shared__ __align__(16) unsigned short lA[128 * 32];
  __shared__ __align__(16) unsigned short lB[BNT * 32];
  const int tid = threadIdx.x;
  const int w = tid >> 6, lane = tid & 63;
  const int lr = lane & 15, lq = lane >> 4;
  const int l = blockIdx.x;
  const int xcd = l & 7, r = l >> 3;
  const int bm = xcd * WM + (r % WM);
  const int rest = r / WM;
  const int bn = rest % NBN;
  const size_t koff = (size_t)(rest / NBN) * K;  // split-K offset (K = per-block K)
  const unsigned short* Ab = A + (size_t)bm * 128 * lda + koff;
  const unsigned short* Bb = Bw + (size_t)bn * BNT * ldb + koff;
  const int wm = (w & 1) << 6;
  const int wn = (w >> 1) * (16 * NJ);
  f32x4 acc[4][NJ] = {};
  const int kiters = K >> 5;
  const int c0 = tid, c1 = 256 + tid;
  const int r0 = c0 >> 2, o0 = (c0 & 3) << 3;
  const int r1 = c1 >> 2, o1 = (c1 & 3) << 3;
  for (int kt = 0; kt < kiters; ++kt) {
    const int kb = kt << 5;
    __syncthreads();
    async16(Ab + (size_t)r0 * lda + kb + o0, lA + c0 * 8);
    async16(Ab + (size_t)r1 * lda + kb + o1, lA + c1 * 8);
    async16(Bb + (size_t)r0 * ldb + kb + o0, lB + c0 * 8);
    if (BNT == 128) async16(Bb + (size_t)r1 * ldb + kb + o1, lB + c1 * 8);
    __syncthreads();
    bf16x8 af[4], bfr[NJ];
#pragma unroll
    for (int i = 0; i < 4; ++i) af[i] = *(const bf16x8*)(lA + (wm + i * 16 + lr) * 32 + lq * 8);
#pragma unroll
    for (int j = 0; j < NJ; ++j) bfr[j] = *(const bf16x8*)(lB + (wn + j * 16 + lr) * 32 + lq * 8);
#pragma unroll
    for (int i = 0; i < 4; ++i)
#pragma unroll
      for (int j = 0; j < NJ; ++j)
        acc[i][j] = __builtin_amdgcn_mfma_f32_16x16x32_bf16(af[i], bfr[j], acc[i][j], 0, 0, 0);
  }
  const int which = (bn * BNT) >> 10;  // EPI5: 0=Q,1=K,2=V (block-uniform; 1024%BNT==0)
#pragma unroll
  for (int i = 0; i < 4; ++i) {
#pragma unroll
    for (int j = 0; j < NJ; ++j) {
      const int colg = bn * BNT + wn + j * 16 + lr;
      const float bi = (EPI == 6) ? 0.f : bias[colg];
      const int rowg0 = bm * 128 + wm + i * 16 + lq * 4;
#pragma unroll
      for (int r2 = 0; r2 < 4; ++r2) {
        const int rowg = rowg0 + r2;
        const float val = acc[i][j][r2] + bi;
        if (EPI == 5) {
          const int t = rowg >> 4, bb = rowg & 15;
          const int hh = (colg >> 6) & 15, dd = colg & 63;
          const size_t nn = (size_t)(bb * 16 + hh);
          unsigned short* q16 = (unsigned short*)Cout;
          if (which == 0) {
            if (rowg >= 1024) q16[(nn * 384 + (t - 64)) * 64 + dd] = f2bf(val);
          } else if (which == 1) {
            q16[KOFF + (nn * 448 + t) * 64 + dd] = f2bf(val);
          } else {
            q16[VOFF + (nn * 448 + t) * 64 + dd] = f2bf(val);
          }
        } else {
          const size_t idx = (size_t)rowg * N + colg;
          if (EPI == 2) ((float*)Cout)[idx] = val + resid[idx];
          else if (EPI == 3) ((unsigned short*)Cout)[idx] = f2bf(fmaxf(val, 0.f));
          else if (EPI == 6) atomicAdd(&((float*)Cout)[idx], acc[i][j][r2]);
        }
      }
    }
  }
}

// ---------------- V transpose: vb[n][t][d] -> vt[n][d][t] ----------------
__global__ __launch_bounds__(256) void vtrans(const unsigned short* __restrict__ vb,
                                              unsigned short* __restrict__ vt) {
  __shared__ __align__(16) unsigned short ls[64][80];
  const int kc = blockIdx.x, n = blockIdx.y;
  const int tid = threadIdx.x;
#pragma unroll
  for (int i = 0; i < 2; ++i) {
    const int c = i * 256 + tid;
    const int kk = c >> 3, dc = (c & 7) << 3;
    u16x8 val = *(const u16x8*)(vb + ((size_t)n * 448 + kc * 64 + kk) * 64 + dc);
    *(u16x8*)&ls[kk][dc] = val;
  }
  __syncthreads();
#pragma unroll
  for (int i = 0; i < 2; ++i) {
    const int c = i * 256 + tid;
    const int d = c >> 3, kx = (c & 7) << 3;
    u16x8 o;
#pragma unroll
    for (int j = 0; j < 8; ++j) o[j] = ls[kx + j][d];
    *(u16x8*)(vt + ((size_t)n * 64 + d) * 448 + kc * 64 + kx) = o;
  }
}

// ---------------- fused attention, S^T formulation, 4 waves/block ----------------
#define PST 468  // P row stride (u16): dword stride 234 == 10 mod 32 -> ~2-way (free)
__global__ __launch_bounds__(256) void attn_kernel(
    const unsigned short* __restrict__ qt_, const unsigned short* __restrict__ kt_,
    const unsigned short* __restrict__ vt_, unsigned short* __restrict__ attn) {
  __shared__ __align__(16) unsigned short P[16 * PST];  // 14976 B
  __shared__ float Rm[4][16], Rs[4][16], Rc[4][16], Rv[4][16], R2[4][16];
  __shared__ __align__(16) float OT[4][16][17];         // per-wave transpose buffers
  const int id = blockIdx.x;
  const int xcd = id & 7, j0 = id >> 3;
  const int n = xcd * 32 + (j0 & 31), qt = j0 >> 5;  // qt 0..23
  const int b = n >> 4, h = n & 15;
  const int tid = threadIdx.x, w = tid >> 6, lane = tid & 63;
  const int lr = lane & 15, lq = lane >> 4;

  const unsigned short* qp = qt_ + ((size_t)n * 384 + qt * 16 + lr) * 64 + lq * 8;
  const bf16x8 q0 = *(const bf16x8*)qp;
  const bf16x8 q1 = *(const bf16x8*)(qp + 32);

  // phase 1: S^T for 7 k-tiles. acc[t][r] = S[q=lr][k = (w*7+t)*16 + 4*lq + r]
  f32x4 acc[7];
#pragma unroll
  for (int t = 0; t < 7; ++t) {
    const unsigned short* kp = kt_ + ((size_t)n * 448 + (w * 7 + t) * 16 + lr) * 64 + lq * 8;
    const bf16x8 k0 = *(const bf16x8*)kp;
    const bf16x8 k1 = *(const bf16x8*)(kp + 32);
    f32x4 a = {0.f, 0.f, 0.f, 0.f};
    a = __builtin_amdgcn_mfma_f32_16x16x32_bf16(k0, q0, a, 0, 0, 0);
    a = __builtin_amdgcn_mfma_f32_16x16x32_bf16(k1, q1, a, 0, 0, 0);
    acc[t] = a;
  }

  // ---- pass 1: row max ----
  f32x4 m4 = acc[0];
#pragma unroll
  for (int t = 1; t < 7; ++t) {
    m4[0] = fmaxf(m4[0], acc[t][0]); m4[1] = fmaxf(m4[1], acc[t][1]);
    m4[2] = fmaxf(m4[2], acc[t][2]); m4[3] = fmaxf(m4[3], acc[t][3]);
  }
  float m = fmaxf(fmaxf(m4[0], m4[1]), fmaxf(m4[2], m4[3]));
  m = fmaxf(m, __shfl_xor(m, 16));
  m = fmaxf(m, __shfl_xor(m, 32));
  if (lq == 0) Rm[w][lr] = m;
  __syncthreads();
  m = fmaxf(fmaxf(Rm[0][lr], Rm[1][lr]), fmaxf(Rm[2][lr], Rm[3][lr]));

  // ---- exp in place; pass 2: sum + nonzero count ----
  f32x4 s4 = {0.f, 0.f, 0.f, 0.f}, c4 = {0.f, 0.f, 0.f, 0.f};
#pragma unroll
  for (int t = 0; t < 7; ++t) {
#pragma unroll
    for (int r = 0; r < 4; ++r) {
      const float e = __expf(acc[t][r] - m);
      acc[t][r] = e;
      s4[r] += e;
      if (e > 0.f) c4[r] += 1.f;
    }
  }
  float s = (s4[0] + s4[1]) + (s4[2] + s4[3]);
  float cnt = (c4[0] + c4[1]) + (c4[2] + c4[3]);
  s += __shfl_xor(s, 16); s += __shfl_xor(s, 32);
  cnt += __shfl_xor(cnt, 16); cnt += __shfl_xor(cnt, 32);
  if (lq == 0) { Rs[w][lr] = s; Rc[w][lr] = cnt; }
  __syncthreads();
  s = (Rs[0][lr] + Rs[1][lr]) + (Rs[2][lr] + Rs[3][lr]);
  cnt = (Rc[0][lr] + Rc[1][lr]) + (Rc[2][lr] + Rc[3][lr]);
  const float inv = 1.f / s;
  const float mean = 1.f / cnt;  // sum(p) == 1

  // ---- pass 3: variance of p over nonzeros ----
  f32x4 d4 = {0.f, 0.f, 0.f, 0.f};
#pragma unroll
  for (int t = 0; t < 7; ++t) {
#pragma unroll
    for (int r = 0; r < 4; ++r) {
      const float p = acc[t][r] * inv;
      const float dd = p - mean;
      if (acc[t][r] > 0.f) d4[r] += dd * dd;
    }
  }
  float dv = (d4[0] + d4[1]) + (d4[2] + d4[3]);
  dv += __shfl_xor(dv, 16); dv += __shfl_xor(dv, 32);
  if (lq == 0) Rv[w][lr] = dv;
  __syncthreads();
  dv = (Rv[0][lr] + Rv[1][lr]) + (Rv[2][lr] + Rv[3][lr]);
  const float thr = mean - 0.5f * sqrtf(dv / (cnt - 1.f));

  // ---- pass 4: survivor renormalizer (row max always survives: p_max >= mean >= thr) ----
  f32x4 t4 = {0.f, 0.f, 0.f, 0.f};
#pragma unroll
  for (int t = 0; t < 7; ++t) {
#pragma unroll
    for (int r = 0; r < 4; ++r) {
      if (!(acc[t][r] * inv < thr)) t4[r] += acc[t][r];
    }
  }
  float s2 = (t4[0] + t4[1]) + (t4[2] + t4[3]);
  s2 += __shfl_xor(s2, 16); s2 += __shfl_xor(s2, 32);
  if (lq == 0) R2[w][lr] = s2;
  __syncthreads();
  s2 = (R2[0][lr] + R2[1][lr]) + (R2[2][lr] + R2[3][lr]);
  const float inv2 = 1.f / s2;

  // ---- write P[q=lr][k] bf16 (wave w covers k in [w*112, w*112+112)) ----
#pragma unroll
  for (int t = 0; t < 7; ++t) {
#pragma unroll
    for (int rp = 0; rp < 4; rp += 2) {
      const float v0 = (acc[t][rp] * inv < thr) ? 0.f : acc[t][rp] * inv2;
      const float v1 = (acc[t][rp + 1] * inv < thr) ? 0.f : acc[t][rp + 1] * inv2;
      const unsigned int u = (unsigned int)f2bf(v0) | ((unsigned int)f2bf(v1) << 16);
      *(unsigned int*)&P[lr * PST + (w * 7 + t) * 16 + lq * 4 + rp] = u;
    }
  }
  __syncthreads();

  // phase 3: out^T[d][q] = V^T(64x448) . P(448x16). Wave w owns d-tile [w*16, w*16+16).
  f32x4 o = {0.f, 0.f, 0.f, 0.f};
#pragma unroll
  for (int c = 0; c < 14; ++c) {
    union { ushort4 hh[2]; bf16x8 v; } bf;
    bf.hh[0] = *(const ushort4*)&P[lr * PST + c * 32 + lq * 8];
    bf.hh[1] = *(const ushort4*)&P[lr * PST + c * 32 + lq * 8 + 4];
    const bf16x8 a = *(const bf16x8*)(vt_ + ((size_t)n * 64 + w * 16 + lr) * 448 + c * 32 + lq * 8);
    o = __builtin_amdgcn_mfma_f32_16x16x32_bf16(a, bf.v, o, 0, 0, 0);
  }

  // transpose 16x16 tile via wave-private LDS (no barrier: same-wave write->read)
#pragma unroll
  for (int r = 0; r < 4; ++r) OT[w][lq * 4 + r][lr] = o[r];
  const int qrow = lane >> 2, dg = lane & 3;
  ushort4 ov;
  ov.x = f2bf(OT[w][dg * 4 + 0][qrow]);
  ov.y = f2bf(OT[w][dg * 4 + 1][qrow]);
  ov.z = f2bf(OT[w][dg * 4 + 2][qrow]);
  ov.w = f2bf(OT[w][dg * 4 + 3][qrow]);
  *(ushort4*)(attn + ((size_t)(qt * 16 + qrow) * 16 + b) * 1024 + h * 64 + w * 16 + dg * 4) = ov;
}

// ---------------- launch ----------------
extern "C" void kernel_launch(void* const* d_in, const int* in_sizes, int n_in,
                              void* d_out, int out_size, void* d_ws, size_t ws_size,
                              hipStream_t stream) {
  (void)in_sizes; (void)n_in; (void)out_size; (void)ws_size;
  const float* x    = (const float*)d_in[0];
  const float* mem  = (const float*)d_in[1];
  const float* q_w  = (const float*)d_in[2];
  const float* q_b  = (const float*)d_in[3];
  const float* k_w  = (const float*)d_in[4];
  const float* k_b  = (const float*)d_in[5];
  const float* v_w  = (const float*)d_in[6];
  const float* v_b  = (const float*)d_in[7];
  const float* o_w  = (const float*)d_in[8];
  const float* o_b  = (const float*)d_in[9];
  const float* ln1w = (const float*)d_in[10];
  const float* ln1b = (const float*)d_in[11];
  const float* f1w  = (const float*)d_in[12];
  const float* f1b  = (const float*)d_in[13];
  const float* f2w  = (const float*)d_in[14];
  const float* f2b  = (const float*)d_in[15];
  const float* ln2w = (const float*)d_in[16];
  const float* ln2b = (const float*)d_in[17];

  unsigned short* WQ   = (unsigned short*)d_ws;        // 3x 1048576 contiguous = fused B
  unsigned short* WK   = WQ + 1048576;
  unsigned short* WV   = WK + 1048576;
  unsigned short* WO   = WV + 1048576;
  unsigned short* WF1  = WO + 1048576;                 // 4194304
  unsigned short* WF2  = WF1 + 4194304;                // 4194304
  unsigned short* ABUF = WF2 + 4194304;                // 7340032 (mem rows 0..1023, xn rows 1024..7167)
  unsigned short* QB   = ABUF + 7340032;               // 6291456 [n][384][64]; KB/VB at KOFF/VOFF
  unsigned short* KB   = QB + 6291456;                 // 7340032 [n][448][64]
  unsigned short* VB   = KB + 7340032;                 // 7340032 [n][448][64]
  unsigned short* VT   = VB + 7340032;                 // 7340032 [n][64][448]
  unsigned short* ATTN = VT + 7340032;                 // 6291456
  float*          X2   = (float*)(ATTN + 6291456);     // 6291456 f32
  float*          QKVB = (float*)ATTN;                 // 3072 f32, dead before attn writes ATTN
  unsigned short* XN2  = ATTN;                         // alias (attn dead after out-proj)
  unsigned short* HB   = ABUF;                         // alias (A/q/k/v staging dead after attention)

  // all weight/memory converts + bias concat in ONE launch
  cvt_all<<<13324, 256, 0, stream>>>(q_w, k_w, v_w, o_w, f1w, f2w, mem, q_b, k_b, v_b,
                                     WQ, WK, WV, WO, WF1, WF2, ABUF, QKVB);

  // LN1 -> xn (rows 1024.. of ABUF)
  ln_bf16<0><<<6144, 256, 0, stream>>>(x, ABUF + 1048576, ln1w, ln1b, nullptr, nullptr);

  // fused QKV: [mem;xn] x [Wq;Wk;Wv]^T, head-major epilogue. NBM=56 -> WM=7, NBN=24.
  gemm_bt<5, 128><<<1344, 256, 0, stream>>>(ABUF, WQ, QKVB, nullptr, QB, 7168, 3072, 1024, 1024, 1024, 24, 7);

  vtrans<<<dim3(7, 256), 256, 0, stream>>>(VB, VT);
  attn_kernel<<<6144, 256, 0, stream>>>(QB, KB, VT, ATTN);

  // out-proj + residual -> X2 (f32). BNT=64: grid 768 = 8 XCD x (6 m x 16 n)
  // = 3 blocks/CU (was 384 = 1.5 — worst co-residency in the app).
  gemm_bt<2, 64><<<768, 256, 0, stream>>>(ATTN, WO, o_b, x, X2, 6144, 1024, 1024, 1024, 1024, 16, 6);

  // LN2 -> xn2, and prefill d_out = X2 + fc2_bias (fc2 accumulates into it)
  ln_bf16<1><<<6144, 256, 0, stream>>>(X2, XN2, ln2w, ln2b, f2b, (float*)d_out);

  // FFN.
  // fc1: BNT=128 proven config, grid 1536 = 8 XCD x (6 m x 32 n) = 6 blocks/CU.
  gemm_bt<3, 128><<<1536, 256, 0, stream>>>(XN2, WF1, f1b, nullptr, HB, 6144, 4096, 1024, 1024, 1024, 32, 6);
  // fc2: BNT=64 + split-K 2: grid 1536 = 8 XCD x (6 m x 16 n x 2 kz) = 6 blocks/CU
  //      with IDENTICAL HBM bytes as the 95.5us round-9 config (WRITE 49MB, kz=2);
  //      atomicAdd f32 into ln2-prefilled d_out.
  gemm_bt<6, 64><<<1536, 256, 0, stream>>>(HB, WF2, nullptr, nullptr, d_out, 6144, 1024, 2048, 4096, 4096, 16, 6);
}

// Round 11
// 501.696 us; speedup vs baseline: 1.0156x; 1.0156x over previous
//
#include <hip/hip_runtime.h>

// ---------------- types / helpers ----------------
typedef __bf16 bf16x8 __attribute__((ext_vector_type(8)));
typedef float f32x4 __attribute__((ext_vector_type(4)));
typedef unsigned short u16x8 __attribute__((ext_vector_type(8)));

__device__ __forceinline__ unsigned short f2bf(float f) {
  union { float f; unsigned int u; } v; v.f = f;
  unsigned int r = v.u + 0x7fffu + ((v.u >> 16) & 1u);  // RNE
  return (unsigned short)(r >> 16);
}

__device__ __forceinline__ void async16(const unsigned short* g, unsigned short* l) {
  __builtin_amdgcn_global_load_lds(
      (const __attribute__((address_space(1))) unsigned int*)g,
      (__attribute__((address_space(3))) unsigned int*)l, 16, 0, 0);
}

// ---------------- fused converts: all weights + memory + bias concat, ONE launch ------
__global__ void cvt_all(const float* __restrict__ q_w, const float* __restrict__ k_w,
                        const float* __restrict__ v_w, const float* __restrict__ o_w,
                        const float* __restrict__ f1w, const float* __restrict__ f2w,
                        const float* __restrict__ mem,
                        const float* __restrict__ q_b, const float* __restrict__ k_b,
                        const float* __restrict__ v_b,
                        unsigned short* __restrict__ WQ, unsigned short* __restrict__ WK,
                        unsigned short* __restrict__ WV, unsigned short* __restrict__ WO,
                        unsigned short* __restrict__ WF1, unsigned short* __restrict__ WF2,
                        unsigned short* __restrict__ MEMB, float* __restrict__ QKVB) {
  const int bid = blockIdx.x;
  const float* src; unsigned short* dst; float scale = 1.f; int base;
  if (bid < 1024)       { src = q_w; dst = WQ;  scale = 0.125f; base = 0; }
  else if (bid < 2048)  { src = k_w; dst = WK;  base = 1024; }
  else if (bid < 3072)  { src = v_w; dst = WV;  base = 2048; }
  else if (bid < 4096)  { src = o_w; dst = WO;  base = 3072; }
  else if (bid < 8192)  { src = f1w; dst = WF1; base = 4096; }
  else if (bid < 12288) { src = f2w; dst = WF2; base = 8192; }
  else if (bid < 13312) { src = mem; dst = MEMB; base = 12288; }
  else {  // bias concat (12 blocks, 3072 elems), q-bias pre-scaled
    const int i = (bid - 13312) * 256 + threadIdx.x;
    QKVB[i] = (i < 1024) ? q_b[i] * 0.125f : (i < 2048 ? k_b[i - 1024] : v_b[i - 2048]);
    return;
  }
  const int i = (bid - base) * 256 + threadIdx.x;
  float4 v = ((const float4*)src)[i];
  ushort4 o;
  o.x = f2bf(v.x * scale); o.y = f2bf(v.y * scale);
  o.z = f2bf(v.z * scale); o.w = f2bf(v.w * scale);
  ((ushort4*)dst)[i] = o;
}

// ---------------- LayerNorm (per 1024-row) -> bf16 ----------------
template <int PREFILL>
__global__ __launch_bounds__(256) void ln_bf16(
    const float* __restrict__ src, unsigned short* __restrict__ dst,
    const float* __restrict__ g, const float* __restrict__ be,
    const float* __restrict__ fbias, float* __restrict__ dout) {
  const int row = blockIdx.x, tid = threadIdx.x;
  const float4 v = ((const float4*)(src + (size_t)row * 1024))[tid];
  if (PREFILL) {
    const float4 fb = ((const float4*)fbias)[tid];
    float4 r;
    r.x = v.x + fb.x; r.y = v.y + fb.y; r.z = v.z + fb.z; r.w = v.w + fb.w;
    ((float4*)(dout + (size_t)row * 1024))[tid] = r;
  }
  float s = v.x + v.y + v.z + v.w;
  float qq = v.x * v.x + v.y * v.y + v.z * v.z + v.w * v.w;
#pragma unroll
  for (int off = 32; off; off >>= 1) { s += __shfl_xor(s, off); qq += __shfl_xor(qq, off); }
  __shared__ float ps[4], pq[4];
  const int w = tid >> 6, lane = tid & 63;
  if (lane == 0) { ps[w] = s; pq[w] = qq; }
  __syncthreads();
  if (tid == 0) { ps[0] = ps[0] + ps[1] + ps[2] + ps[3]; pq[0] = pq[0] + pq[1] + pq[2] + pq[3]; }
  __syncthreads();
  const float mu = ps[0] * (1.f / 1024.f);
  const float var = pq[0] * (1.f / 1024.f) - mu * mu;
  const float rs = rsqrtf(var + 1e-5f);
  const float4 gv = ((const float4*)g)[tid];
  const float4 bv = ((const float4*)be)[tid];
  ushort4 o;
  o.x = f2bf((v.x - mu) * rs * gv.x + bv.x);
  o.y = f2bf((v.y - mu) * rs * gv.y + bv.y);
  o.z = f2bf((v.z - mu) * rs * gv.z + bv.z);
  o.w = f2bf((v.w - mu) * rs * gv.w + bv.w);
  ((ushort4*)(dst + (size_t)row * 1024))[tid] = o;
}

// ---------------- GEMM: C[M,N] = A[M,K] @ B[N,K]^T (+ bias), m97-style ----------------
// SESSION LEDGER (r1-10): deep-pipeline engines (2-phase, +T2 swizzle, depth-3 ring)
// all parity-or-worse — latency-bound at 1 block/CU; this 256-thr/small-LDS kernel
// keeps 3-6 blocks/CU and m114 implicit wave overlap pipelines for free.
// Per-op measured optima:
//   fc1: BNT=128 grid 1536 (6 blk/CU) — ~20us faster than 768-class.
//   fc2: BNT=128 splitK2 grid 768 = 95.5us. splitK4 = 131 (+47MB atomics);
//        BNT=64 splitK2 grid 1536 = 112 (r10: half the MFMA per barrier pair —
//        per-MFMA sync overhead doubles; occupancy 52% can't buy it back).
//   outproj: BNT=64 grid 768 (3 blk/CU; was 1.5 — kept, neutral-to-positive).
// Lesson: blocks/CU helps only at CONSTANT work-per-barrier; shrinking the tile
// to get blocks is net-negative.
// (256,4): reg cap 128 — no spill ((256,8) forced VGPR=32 -> scratch catastrophe,
// round 2); floor-guarantee only.
#define KOFF 6291456ull
#define VOFF 13631488ull
template <int EPI, int BNT>
__global__ __launch_bounds__(256, 4) void gemm_bt(
    const unsigned short* __restrict__ A, const unsigned short* __restrict__ Bw,
    const float* __restrict__ bias, const float* __restrict__ resid,
    void* __restrict__ Cout, int M, int N, int K, int lda, int ldb, int NBN, int WM) {
  constexpr int NJ = BNT / 32;  // B-frags per wave; wave covers 16*NJ cols
  __shared__ __align__(16) unsigned short lA[128 * 32];
  __shared__ __align__(16) unsigned short lB[BNT * 32];
  const int tid = threadIdx.x;
  const int w = tid >> 6, lane = tid & 63;
  const int lr = lane & 15, lq = lane >> 4;
  const int l = blockIdx.x;
  const int xcd = l & 7, r = l >> 3;
  const int bm = xcd * WM + (r % WM);
  const int rest = r / WM;
  const int bn = rest % NBN;
  const size_t koff = (size_t)(rest / NBN) * K;  // split-K offset (K = per-block K)
  const unsigned short* Ab = A + (size_t)bm * 128 * lda + koff;
  const unsigned short* Bb = Bw + (size_t)bn * BNT * ldb + koff;
  const int wm = (w & 1) << 6;
  const int wn = (w >> 1) * (16 * NJ);
  f32x4 acc[4][NJ] = {};
  const int kiters = K >> 5;
  const int c0 = tid, c1 = 256 + tid;
  const int r0 = c0 >> 2, o0 = (c0 & 3) << 3;
  const int r1 = c1 >> 2, o1 = (c1 & 3) << 3;
  for (int kt = 0; kt < kiters; ++kt) {
    const int kb = kt << 5;
    __syncthreads();
    async16(Ab + (size_t)r0 * lda + kb + o0, lA + c0 * 8);
    async16(Ab + (size_t)r1 * lda + kb + o1, lA + c1 * 8);
    async16(Bb + (size_t)r0 * ldb + kb + o0, lB + c0 * 8);
    if (BNT == 128) async16(Bb + (size_t)r1 * ldb + kb + o1, lB + c1 * 8);
    __syncthreads();
    bf16x8 af[4], bfr[NJ];
#pragma unroll
    for (int i = 0; i < 4; ++i) af[i] = *(const bf16x8*)(lA + (wm + i * 16 + lr) * 32 + lq * 8);
#pragma unroll
    for (int j = 0; j < NJ; ++j) bfr[j] = *(const bf16x8*)(lB + (wn + j * 16 + lr) * 32 + lq * 8);
#pragma unroll
    for (int i = 0; i < 4; ++i)
#pragma unroll
      for (int j = 0; j < NJ; ++j)
        acc[i][j] = __builtin_amdgcn_mfma_f32_16x16x32_bf16(af[i], bfr[j], acc[i][j], 0, 0, 0);
  }
  const int which = (bn * BNT) >> 10;  // EPI5: 0=Q,1=K,2=V (block-uniform; 1024%BNT==0)
#pragma unroll
  for (int i = 0; i < 4; ++i) {
#pragma unroll
    for (int j = 0; j < NJ; ++j) {
      const int colg = bn * BNT + wn + j * 16 + lr;
      const float bi = (EPI == 6) ? 0.f : bias[colg];
      const int rowg0 = bm * 128 + wm + i * 16 + lq * 4;
#pragma unroll
      for (int r2 = 0; r2 < 4; ++r2) {
        const int rowg = rowg0 + r2;
        const float val = acc[i][j][r2] + bi;
        if (EPI == 5) {
          const int t = rowg >> 4, bb = rowg & 15;
          const int hh = (colg >> 6) & 15, dd = colg & 63;
          const size_t nn = (size_t)(bb * 16 + hh);
          unsigned short* q16 = (unsigned short*)Cout;
          if (which == 0) {
            if (rowg >= 1024) q16[(nn * 384 + (t - 64)) * 64 + dd] = f2bf(val);
          } else if (which == 1) {
            q16[KOFF + (nn * 448 + t) * 64 + dd] = f2bf(val);
          } else {
            q16[VOFF + (nn * 448 + t) * 64 + dd] = f2bf(val);
          }
        } else {
          const size_t idx = (size_t)rowg * N + colg;
          if (EPI == 2) ((float*)Cout)[idx] = val + resid[idx];
          else if (EPI == 3) ((unsigned short*)Cout)[idx] = f2bf(fmaxf(val, 0.f));
          else if (EPI == 6) atomicAdd(&((float*)Cout)[idx], acc[i][j][r2]);
        }
      }
    }
  }
}

// ---------------- V transpose: vb[n][t][d] -> vt[n][d][t] ----------------
__global__ __launch_bounds__(256) void vtrans(const unsigned short* __restrict__ vb,
                                              unsigned short* __restrict__ vt) {
  __shared__ __align__(16) unsigned short ls[64][80];
  const int kc = blockIdx.x, n = blockIdx.y;
  const int tid = threadIdx.x;
#pragma unroll
  for (int i = 0; i < 2; ++i) {
    const int c = i * 256 + tid;
    const int kk = c >> 3, dc = (c & 7) << 3;
    u16x8 val = *(const u16x8*)(vb + ((size_t)n * 448 + kc * 64 + kk) * 64 + dc);
    *(u16x8*)&ls[kk][dc] = val;
  }
  __syncthreads();
#pragma unroll
  for (int i = 0; i < 2; ++i) {
    const int c = i * 256 + tid;
    const int d = c >> 3, kx = (c & 7) << 3;
    u16x8 o;
#pragma unroll
    for (int j = 0; j < 8; ++j) o[j] = ls[kx + j][d];
    *(u16x8*)(vt + ((size_t)n * 64 + d) * 448 + kc * 64 + kx) = o;
  }
}

// ---------------- fused attention, S^T formulation, 4 waves/block ----------------
#define PST 468  // P row stride (u16): dword stride 234 == 10 mod 32 -> ~2-way (free)
__global__ __launch_bounds__(256) void attn_kernel(
    const unsigned short* __restrict__ qt_, const unsigned short* __restrict__ kt_,
    const unsigned short* __restrict__ vt_, unsigned short* __restrict__ attn) {
  __shared__ __align__(16) unsigned short P[16 * PST];  // 14976 B
  __shared__ float Rm[4][16], Rs[4][16], Rc[4][16], Rv[4][16], R2[4][16];
  __shared__ __align__(16) float OT[4][16][17];         // per-wave transpose buffers
  const int id = blockIdx.x;
  const int xcd = id & 7, j0 = id >> 3;
  const int n = xcd * 32 + (j0 & 31), qt = j0 >> 5;  // qt 0..23
  const int b = n >> 4, h = n & 15;
  const int tid = threadIdx.x, w = tid >> 6, lane = tid & 63;
  const int lr = lane & 15, lq = lane >> 4;

  const unsigned short* qp = qt_ + ((size_t)n * 384 + qt * 16 + lr) * 64 + lq * 8;
  const bf16x8 q0 = *(const bf16x8*)qp;
  const bf16x8 q1 = *(const bf16x8*)(qp + 32);

  // phase 1: S^T for 7 k-tiles. acc[t][r] = S[q=lr][k = (w*7+t)*16 + 4*lq + r]
  f32x4 acc[7];
#pragma unroll
  for (int t = 0; t < 7; ++t) {
    const unsigned short* kp = kt_ + ((size_t)n * 448 + (w * 7 + t) * 16 + lr) * 64 + lq * 8;
    const bf16x8 k0 = *(const bf16x8*)kp;
    const bf16x8 k1 = *(const bf16x8*)(kp + 32);
    f32x4 a = {0.f, 0.f, 0.f, 0.f};
    a = __builtin_amdgcn_mfma_f32_16x16x32_bf16(k0, q0, a, 0, 0, 0);
    a = __builtin_amdgcn_mfma_f32_16x16x32_bf16(k1, q1, a, 0, 0, 0);
    acc[t] = a;
  }

  // ---- pass 1: row max ----
  f32x4 m4 = acc[0];
#pragma unroll
  for (int t = 1; t < 7; ++t) {
    m4[0] = fmaxf(m4[0], acc[t][0]); m4[1] = fmaxf(m4[1], acc[t][1]);
    m4[2] = fmaxf(m4[2], acc[t][2]); m4[3] = fmaxf(m4[3], acc[t][3]);
  }
  float m = fmaxf(fmaxf(m4[0], m4[1]), fmaxf(m4[2], m4[3]));
  m = fmaxf(m, __shfl_xor(m, 16));
  m = fmaxf(m, __shfl_xor(m, 32));
  if (lq == 0) Rm[w][lr] = m;
  __syncthreads();
  m = fmaxf(fmaxf(Rm[0][lr], Rm[1][lr]), fmaxf(Rm[2][lr], Rm[3][lr]));

  // ---- exp in place; pass 2: sum + nonzero count ----
  f32x4 s4 = {0.f, 0.f, 0.f, 0.f}, c4 = {0.f, 0.f, 0.f, 0.f};
#pragma unroll
  for (int t = 0; t < 7; ++t) {
#pragma unroll
    for (int r = 0; r < 4; ++r) {
      const float e = __expf(acc[t][r] - m);
      acc[t][r] = e;
      s4[r] += e;
      if (e > 0.f) c4[r] += 1.f;
    }
  }
  float s = (s4[0] + s4[1]) + (s4[2] + s4[3]);
  float cnt = (c4[0] + c4[1]) + (c4[2] + c4[3]);
  s += __shfl_xor(s, 16); s += __shfl_xor(s, 32);
  cnt += __shfl_xor(cnt, 16); cnt += __shfl_xor(cnt, 32);
  if (lq == 0) { Rs[w][lr] = s; Rc[w][lr] = cnt; }
  __syncthreads();
  s = (Rs[0][lr] + Rs[1][lr]) + (Rs[2][lr] + Rs[3][lr]);
  cnt = (Rc[0][lr] + Rc[1][lr]) + (Rc[2][lr] + Rc[3][lr]);
  const float inv = 1.f / s;
  const float mean = 1.f / cnt;  // sum(p) == 1

  // ---- pass 3: variance of p over nonzeros ----
  f32x4 d4 = {0.f, 0.f, 0.f, 0.f};
#pragma unroll
  for (int t = 0; t < 7; ++t) {
#pragma unroll
    for (int r = 0; r < 4; ++r) {
      const float p = acc[t][r] * inv;
      const float dd = p - mean;
      if (acc[t][r] > 0.f) d4[r] += dd * dd;
    }
  }
  float dv = (d4[0] + d4[1]) + (d4[2] + d4[3]);
  dv += __shfl_xor(dv, 16); dv += __shfl_xor(dv, 32);
  if (lq == 0) Rv[w][lr] = dv;
  __syncthreads();
  dv = (Rv[0][lr] + Rv[1][lr]) + (Rv[2][lr] + Rv[3][lr]);
  const float thr = mean - 0.5f * sqrtf(dv / (cnt - 1.f));

  // ---- pass 4: survivor renormalizer (row max always survives: p_max >= mean >= thr) ----
  f32x4 t4 = {0.f, 0.f, 0.f, 0.f};
#pragma unroll
  for (int t = 0; t < 7; ++t) {
#pragma unroll
    for (int r = 0; r < 4; ++r) {
      if (!(acc[t][r] * inv < thr)) t4[r] += acc[t][r];
    }
  }
  float s2 = (t4[0] + t4[1]) + (t4[2] + t4[3]);
  s2 += __shfl_xor(s2, 16); s2 += __shfl_xor(s2, 32);
  if (lq == 0) R2[w][lr] = s2;
  __syncthreads();
  s2 = (R2[0][lr] + R2[1][lr]) + (R2[2][lr] + R2[3][lr]);
  const float inv2 = 1.f / s2;

  // ---- write P[q=lr][k] bf16 (wave w covers k in [w*112, w*112+112)) ----
#pragma unroll
  for (int t = 0; t < 7; ++t) {
#pragma unroll
    for (int rp = 0; rp < 4; rp += 2) {
      const float v0 = (acc[t][rp] * inv < thr) ? 0.f : acc[t][rp] * inv2;
      const float v1 = (acc[t][rp + 1] * inv < thr) ? 0.f : acc[t][rp + 1] * inv2;
      const unsigned int u = (unsigned int)f2bf(v0) | ((unsigned int)f2bf(v1) << 16);
      *(unsigned int*)&P[lr * PST + (w * 7 + t) * 16 + lq * 4 + rp] = u;
    }
  }
  __syncthreads();

  // phase 3: out^T[d][q] = V^T(64x448) . P(448x16). Wave w owns d-tile [w*16, w*16+16).
  f32x4 o = {0.f, 0.f, 0.f, 0.f};
#pragma unroll
  for (int c = 0; c < 14; ++c) {
    union { ushort4 hh[2]; bf16x8 v; } bf;
    bf.hh[0] = *(const ushort4*)&P[lr * PST + c * 32 + lq * 8];
    bf.hh[1] = *(const ushort4*)&P[lr * PST + c * 32 + lq * 8 + 4];
    const bf16x8 a = *(const bf16x8*)(vt_ + ((size_t)n * 64 + w * 16 + lr) * 448 + c * 32 + lq * 8);
    o = __builtin_amdgcn_mfma_f32_16x16x32_bf16(a, bf.v, o, 0, 0, 0);
  }

  // transpose 16x16 tile via wave-private LDS (no barrier: same-wave write->read)
#pragma unroll
  for (int r = 0; r < 4; ++r) OT[w][lq * 4 + r][lr] = o[r];
  const int qrow = lane >> 2, dg = lane & 3;
  ushort4 ov;
  ov.x = f2bf(OT[w][dg * 4 + 0][qrow]);
  ov.y = f2bf(OT[w][dg * 4 + 1][qrow]);
  ov.z = f2bf(OT[w][dg * 4 + 2][qrow]);
  ov.w = f2bf(OT[w][dg * 4 + 3][qrow]);
  *(ushort4*)(attn + ((size_t)(qt * 16 + qrow) * 16 + b) * 1024 + h * 64 + w * 16 + dg * 4) = ov;
}

// ---------------- launch ----------------
extern "C" void kernel_launch(void* const* d_in, const int* in_sizes, int n_in,
                              void* d_out, int out_size, void* d_ws, size_t ws_size,
                              hipStream_t stream) {
  (void)in_sizes; (void)n_in; (void)out_size; (void)ws_size;
  const float* x    = (const float*)d_in[0];
  const float* mem  = (const float*)d_in[1];
  const float* q_w  = (const float*)d_in[2];
  const float* q_b  = (const float*)d_in[3];
  const float* k_w  = (const float*)d_in[4];
  const float* k_b  = (const float*)d_in[5];
  const float* v_w  = (const float*)d_in[6];
  const float* v_b  = (const float*)d_in[7];
  const float* o_w  = (const float*)d_in[8];
  const float* o_b  = (const float*)d_in[9];
  const float* ln1w = (const float*)d_in[10];
  const float* ln1b = (const float*)d_in[11];
  const float* f1w  = (const float*)d_in[12];
  const float* f1b  = (const float*)d_in[13];
  const float* f2w  = (const float*)d_in[14];
  const float* f2b  = (const float*)d_in[15];
  const float* ln2w = (const float*)d_in[16];
  const float* ln2b = (const float*)d_in[17];

  unsigned short* WQ   = (unsigned short*)d_ws;        // 3x 1048576 contiguous = fused B
  unsigned short* WK   = WQ + 1048576;
  unsigned short* WV   = WK + 1048576;
  unsigned short* WO   = WV + 1048576;
  unsigned short* WF1  = WO + 1048576;                 // 4194304
  unsigned short* WF2  = WF1 + 4194304;                // 4194304
  unsigned short* ABUF = WF2 + 4194304;                // 7340032 (mem rows 0..1023, xn rows 1024..7167)
  unsigned short* QB   = ABUF + 7340032;               // 6291456 [n][384][64]; KB/VB at KOFF/VOFF
  unsigned short* KB   = QB + 6291456;                 // 7340032 [n][448][64]
  unsigned short* VB   = KB + 7340032;                 // 7340032 [n][448][64]
  unsigned short* VT   = VB + 7340032;                 // 7340032 [n][64][448]
  unsigned short* ATTN = VT + 7340032;                 // 6291456
  float*          X2   = (float*)(ATTN + 6291456);     // 6291456 f32
  float*          QKVB = (float*)ATTN;                 // 3072 f32, dead before attn writes ATTN
  unsigned short* XN2  = ATTN;                         // alias (attn dead after out-proj)
  unsigned short* HB   = ABUF;                         // alias (A/q/k/v staging dead after attention)

  // all weight/memory converts + bias concat in ONE launch
  cvt_all<<<13324, 256, 0, stream>>>(q_w, k_w, v_w, o_w, f1w, f2w, mem, q_b, k_b, v_b,
                                     WQ, WK, WV, WO, WF1, WF2, ABUF, QKVB);

  // LN1 -> xn (rows 1024.. of ABUF)
  ln_bf16<0><<<6144, 256, 0, stream>>>(x, ABUF + 1048576, ln1w, ln1b, nullptr, nullptr);

  // fused QKV: [mem;xn] x [Wq;Wk;Wv]^T, head-major epilogue. NBM=56 -> WM=7, NBN=24.
  gemm_bt<5, 128><<<1344, 256, 0, stream>>>(ABUF, WQ, QKVB, nullptr, QB, 7168, 3072, 1024, 1024, 1024, 24, 7);

  vtrans<<<dim3(7, 256), 256, 0, stream>>>(VB, VT);
  attn_kernel<<<6144, 256, 0, stream>>>(QB, KB, VT, ATTN);

  // out-proj + residual -> X2 (f32). BNT=64: grid 768 = 8 XCD x (6 m x 16 n)
  // = 3 blocks/CU (kept from r10: was 1.5 blk/CU at BNT=128; work-per-barrier for
  // outproj is 8 MFMA either way, so finer tiles here are co-residency-positive).
  gemm_bt<2, 64><<<768, 256, 0, stream>>>(ATTN, WO, o_b, x, X2, 6144, 1024, 1024, 1024, 1024, 16, 6);

  // LN2 -> xn2, and prefill d_out = X2 + fc2_bias (fc2 accumulates into it)
  ln_bf16<1><<<6144, 256, 0, stream>>>(X2, XN2, ln2w, ln2b, f2b, (float*)d_out);

  // FFN.
  // fc1: BNT=128 proven config, grid 1536 = 8 XCD x (6 m x 32 n) = 6 blocks/CU.
  gemm_bt<3, 128><<<1536, 256, 0, stream>>>(XN2, WF1, f1b, nullptr, HB, 6144, 4096, 1024, 1024, 1024, 32, 6);
  // fc2: REVERTED to round-9 optimum: BNT=128, split-K 2, grid 768 = 8 XCD x
  //      (6 m x 8 n x 2 kz), per-block K=2048 (95.5us; BNT=64@1536 was 112us —
  //      r10 lesson). atomicAdd f32 into ln2-prefilled d_out.
  gemm_bt<6, 128><<<768, 256, 0, stream>>>(HB, WF2, nullptr, nullptr, d_out, 6144, 1024, 2048, 4096, 4096, 8, 6);
}

// Round 12
// 477.757 us; speedup vs baseline: 1.0664x; 1.0501x over previous
//
#include <hip/hip_runtime.h>

// ---------------- types / helpers ----------------
typedef __bf16 bf16x8 __attribute__((ext_vector_type(8)));
typedef float f32x4 __attribute__((ext_vector_type(4)));
typedef unsigned short u16x8 __attribute__((ext_vector_type(8)));

__device__ __forceinline__ unsigned short f2bf(float f) {
  union { float f; unsigned int u; } v; v.f = f;
  unsigned int r = v.u + 0x7fffu + ((v.u >> 16) & 1u);  // RNE
  return (unsigned short)(r >> 16);
}

__device__ __forceinline__ void async16(const unsigned short* g, unsigned short* l) {
  __builtin_amdgcn_global_load_lds(
      (const __attribute__((address_space(1))) unsigned int*)g,
      (__attribute__((address_space(3))) unsigned int*)l, 16, 0, 0);
}

// ---------------- fused converts: all weights + memory + bias concat, ONE launch ------
__global__ void cvt_all(const float* __restrict__ q_w, const float* __restrict__ k_w,
                        const float* __restrict__ v_w, const float* __restrict__ o_w,
                        const float* __restrict__ f1w, const float* __restrict__ f2w,
                        const float* __restrict__ mem,
                        const float* __restrict__ q_b, const float* __restrict__ k_b,
                        const float* __restrict__ v_b,
                        unsigned short* __restrict__ WQ, unsigned short* __restrict__ WK,
                        unsigned short* __restrict__ WV, unsigned short* __restrict__ WO,
                        unsigned short* __restrict__ WF1, unsigned short* __restrict__ WF2,
                        unsigned short* __restrict__ MEMB, float* __restrict__ QKVB) {
  const int bid = blockIdx.x;
  const float* src; unsigned short* dst; float scale = 1.f; int base;
  if (bid < 1024)       { src = q_w; dst = WQ;  scale = 0.125f; base = 0; }
  else if (bid < 2048)  { src = k_w; dst = WK;  base = 1024; }
  else if (bid < 3072)  { src = v_w; dst = WV;  base = 2048; }
  else if (bid < 4096)  { src = o_w; dst = WO;  base = 3072; }
  else if (bid < 8192)  { src = f1w; dst = WF1; base = 4096; }
  else if (bid < 12288) { src = f2w; dst = WF2; base = 8192; }
  else if (bid < 13312) { src = mem; dst = MEMB; base = 12288; }
  else {  // bias concat (12 blocks, 3072 elems), q-bias pre-scaled
    const int i = (bid - 13312) * 256 + threadIdx.x;
    QKVB[i] = (i < 1024) ? q_b[i] * 0.125f : (i < 2048 ? k_b[i - 1024] : v_b[i - 2048]);
    return;
  }
  const int i = (bid - base) * 256 + threadIdx.x;
  float4 v = ((const float4*)src)[i];
  ushort4 o;
  o.x = f2bf(v.x * scale); o.y = f2bf(v.y * scale);
  o.z = f2bf(v.z * scale); o.w = f2bf(v.w * scale);
  ((ushort4*)dst)[i] = o;
}

// ---------------- LayerNorm (per 1024-row) -> bf16 ----------------
template <int PREFILL>
__global__ __launch_bounds__(256) void ln_bf16(
    const float* __restrict__ src, unsigned short* __restrict__ dst,
    const float* __restrict__ g, const float* __restrict__ be,
    const float* __restrict__ fbias, float* __restrict__ dout) {
  const int row = blockIdx.x, tid = threadIdx.x;
  const float4 v = ((const float4*)(src + (size_t)row * 1024))[tid];
  if (PREFILL) {
    const float4 fb = ((const float4*)fbias)[tid];
    float4 r;
    r.x = v.x + fb.x; r.y = v.y + fb.y; r.z = v.z + fb.z; r.w = v.w + fb.w;
    ((float4*)(dout + (size_t)row * 1024))[tid] = r;
  }
  float s = v.x + v.y + v.z + v.w;
  float qq = v.x * v.x + v.y * v.y + v.z * v.z + v.w * v.w;
#pragma unroll
  for (int off = 32; off; off >>= 1) { s += __shfl_xor(s, off); qq += __shfl_xor(qq, off); }
  __shared__ float ps[4], pq[4];
  const int w = tid >> 6, lane = tid & 63;
  if (lane == 0) { ps[w] = s; pq[w] = qq; }
  __syncthreads();
  if (tid == 0) { ps[0] = ps[0] + ps[1] + ps[2] + ps[3]; pq[0] = pq[0] + pq[1] + pq[2] + pq[3]; }
  __syncthreads();
  const float mu = ps[0] * (1.f / 1024.f);
  const float var = pq[0] * (1.f / 1024.f) - mu * mu;
  const float rs = rsqrtf(var + 1e-5f);
  const float4 gv = ((const float4*)g)[tid];
  const float4 bv = ((const float4*)be)[tid];
  ushort4 o;
  o.x = f2bf((v.x - mu) * rs * gv.x + bv.x);
  o.y = f2bf((v.y - mu) * rs * gv.y + bv.y);
  o.z = f2bf((v.z - mu) * rs * gv.z + bv.z);
  o.w = f2bf((v.w - mu) * rs * gv.w + bv.w);
  ((ushort4*)(dst + (size_t)row * 1024))[tid] = o;
}

// ---------------- GEMM: C[M,N] = A[M,K] @ B[N,K]^T (+ bias), m97-style, BK=64 --------
// SESSION LEDGER (r1-11): deep-pipeline engines (1 blk/CU) all fail — latency-bound;
// this 256-thr kernel at 3-6 blk/CU wins via m114 implicit wave overlap. r10: LESS
// work per barrier (BNT=64 fc2) = worse. ROUND 12: MORE work per barrier — BK=64 as
// two 32-col slabs [2][rows][32]; per-slab layout/read pattern byte-identical to the
// proven BK=32 version (64B row stride = 2-way-free banks), 2x16 MFMA between one
// barrier pair, kiters halved. LDS 32 KB (BNT=128) -> still 5 blk/CU possible.
// Per-op measured optima (BK=32 era): fc1 BNT=128@1536; fc2 BNT=128 splitK2@768
// (95.5us; splitK4 and BNT=64 both regressed); outproj BNT=64@768.
// (256,4): reg cap 128 — no spill ((256,8) scratch catastrophe, r2).
#define KOFF 6291456ull
#define VOFF 13631488ull
template <int EPI, int BNT>
__global__ __launch_bounds__(256, 4) void gemm_bt(
    const unsigned short* __restrict__ A, const unsigned short* __restrict__ Bw,
    const float* __restrict__ bias, const float* __restrict__ resid,
    void* __restrict__ Cout, int M, int N, int K, int lda, int ldb, int NBN, int WM) {
  constexpr int NJ = BNT / 32;       // B-frags per wave; wave covers 16*NJ cols
  constexpr int BS = BNT * 32;       // u16 per B slab
  __shared__ __align__(16) unsigned short lA[2 * 128 * 32];  // [slab][128][32]
  __shared__ __align__(16) unsigned short lB[2 * BS];        // [slab][BNT][32]
  const int tid = threadIdx.x;
  const int w = tid >> 6, lane = tid & 63;
  const int lr = lane & 15, lq = lane >> 4;
  const int l = blockIdx.x;
  const int xcd = l & 7, r = l >> 3;
  const int bm = xcd * WM + (r % WM);
  const int rest = r / WM;
  const int bn = rest % NBN;
  const size_t koff = (size_t)(rest / NBN) * K;  // split-K offset (K = per-block K)
  const unsigned short* Ab = A + (size_t)bm * 128 * lda + koff;
  const unsigned short* Bb = Bw + (size_t)bn * BNT * ldb + koff;
  const int wm = (w & 1) << 6;
  const int wn = (w >> 1) * (16 * NJ);
  f32x4 acc[4][NJ] = {};
  const int kiters = K >> 6;         // BK=64
  const int c0 = tid, c1 = 256 + tid;
  const int r0 = c0 >> 2, o0 = (c0 & 3) << 3;
  const int r1 = c1 >> 2, o1 = (c1 & 3) << 3;
  for (int kt = 0; kt < kiters; ++kt) {
    const int kb = kt << 6;
    __syncthreads();
#pragma unroll
    for (int s = 0; s < 2; ++s) {
      const int kc = kb + s * 32;
      async16(Ab + (size_t)r0 * lda + kc + o0, lA + s * 4096 + c0 * 8);
      async16(Ab + (size_t)r1 * lda + kc + o1, lA + s * 4096 + c1 * 8);
      async16(Bb + (size_t)r0 * ldb + kc + o0, lB + s * BS + c0 * 8);
      if (BNT == 128) async16(Bb + (size_t)r1 * ldb + kc + o1, lB + s * BS + c1 * 8);
    }
    __syncthreads();
#pragma unroll
    for (int s = 0; s < 2; ++s) {
      bf16x8 af[4], bfr[NJ];
#pragma unroll
      for (int i = 0; i < 4; ++i)
        af[i] = *(const bf16x8*)(lA + s * 4096 + (wm + i * 16 + lr) * 32 + lq * 8);
#pragma unroll
      for (int j = 0; j < NJ; ++j)
        bfr[j] = *(const bf16x8*)(lB + s * BS + (wn + j * 16 + lr) * 32 + lq * 8);
#pragma unroll
      for (int i = 0; i < 4; ++i)
#pragma unroll
        for (int j = 0; j < NJ; ++j)
          acc[i][j] = __builtin_amdgcn_mfma_f32_16x16x32_bf16(af[i], bfr[j], acc[i][j], 0, 0, 0);
    }
  }
  const int which = (bn * BNT) >> 10;  // EPI5: 0=Q,1=K,2=V (block-uniform; 1024%BNT==0)
#pragma unroll
  for (int i = 0; i < 4; ++i) {
#pragma unroll
    for (int j = 0; j < NJ; ++j) {
      const int colg = bn * BNT + wn + j * 16 + lr;
      const float bi = (EPI == 6) ? 0.f : bias[colg];
      const int rowg0 = bm * 128 + wm + i * 16 + lq * 4;
#pragma unroll
      for (int r2 = 0; r2 < 4; ++r2) {
        const int rowg = rowg0 + r2;
        const float val = acc[i][j][r2] + bi;
        if (EPI == 5) {
          const int t = rowg >> 4, bb = rowg & 15;
          const int hh = (colg >> 6) & 15, dd = colg & 63;
          const size_t nn = (size_t)(bb * 16 + hh);
          unsigned short* q16 = (unsigned short*)Cout;
          if (which == 0) {
            if (rowg >= 1024) q16[(nn * 384 + (t - 64)) * 64 + dd] = f2bf(val);
          } else if (which == 1) {
            q16[KOFF + (nn * 448 + t) * 64 + dd] = f2bf(val);
          } else {
            q16[VOFF + (nn * 448 + t) * 64 + dd] = f2bf(val);
          }
        } else {
          const size_t idx = (size_t)rowg * N + colg;
          if (EPI == 2) ((float*)Cout)[idx] = val + resid[idx];
          else if (EPI == 3) ((unsigned short*)Cout)[idx] = f2bf(fmaxf(val, 0.f));
          else if (EPI == 6) atomicAdd(&((float*)Cout)[idx], acc[i][j][r2]);
        }
      }
    }
  }
}

// ---------------- V transpose: vb[n][t][d] -> vt[n][d][t] ----------------
__global__ __launch_bounds__(256) void vtrans(const unsigned short* __restrict__ vb,
                                              unsigned short* __restrict__ vt) {
  __shared__ __align__(16) unsigned short ls[64][80];
  const int kc = blockIdx.x, n = blockIdx.y;
  const int tid = threadIdx.x;
#pragma unroll
  for (int i = 0; i < 2; ++i) {
    const int c = i * 256 + tid;
    const int kk = c >> 3, dc = (c & 7) << 3;
    u16x8 val = *(const u16x8*)(vb + ((size_t)n * 448 + kc * 64 + kk) * 64 + dc);
    *(u16x8*)&ls[kk][dc] = val;
  }
  __syncthreads();
#pragma unroll
  for (int i = 0; i < 2; ++i) {
    const int c = i * 256 + tid;
    const int d = c >> 3, kx = (c & 7) << 3;
    u16x8 o;
#pragma unroll
    for (int j = 0; j < 8; ++j) o[j] = ls[kx + j][d];
    *(u16x8*)(vt + ((size_t)n * 64 + d) * 448 + kc * 64 + kx) = o;
  }
}

// ---------------- fused attention, S^T formulation, 4 waves/block ----------------
#define PST 468  // P row stride (u16): dword stride 234 == 10 mod 32 -> ~2-way (free)
__global__ __launch_bounds__(256) void attn_kernel(
    const unsigned short* __restrict__ qt_, const unsigned short* __restrict__ kt_,
    const unsigned short* __restrict__ vt_, unsigned short* __restrict__ attn) {
  __shared__ __align__(16) unsigned short P[16 * PST];  // 14976 B
  __shared__ float Rm[4][16], Rs[4][16], Rc[4][16], Rv[4][16], R2[4][16];
  __shared__ __align__(16) float OT[4][16][17];         // per-wave transpose buffers
  const int id = blockIdx.x;
  const int xcd = id & 7, j0 = id >> 3;
  const int n = xcd * 32 + (j0 & 31), qt = j0 >> 5;  // qt 0..23
  const int b = n >> 4, h = n & 15;
  const int tid = threadIdx.x, w = tid >> 6, lane = tid & 63;
  const int lr = lane & 15, lq = lane >> 4;

  const unsigned short* qp = qt_ + ((size_t)n * 384 + qt * 16 + lr) * 64 + lq * 8;
  const bf16x8 q0 = *(const bf16x8*)qp;
  const bf16x8 q1 = *(const bf16x8*)(qp + 32);

  // phase 1: S^T for 7 k-tiles. acc[t][r] = S[q=lr][k = (w*7+t)*16 + 4*lq + r]
  f32x4 acc[7];
#pragma unroll
  for (int t = 0; t < 7; ++t) {
    const unsigned short* kp = kt_ + ((size_t)n * 448 + (w * 7 + t) * 16 + lr) * 64 + lq * 8;
    const bf16x8 k0 = *(const bf16x8*)kp;
    const bf16x8 k1 = *(const bf16x8*)(kp + 32);
    f32x4 a = {0.f, 0.f, 0.f, 0.f};
    a = __builtin_amdgcn_mfma_f32_16x16x32_bf16(k0, q0, a, 0, 0, 0);
    a = __builtin_amdgcn_mfma_f32_16x16x32_bf16(k1, q1, a, 0, 0, 0);
    acc[t] = a;
  }

  // ---- pass 1: row max ----
  f32x4 m4 = acc[0];
#pragma unroll
  for (int t = 1; t < 7; ++t) {
    m4[0] = fmaxf(m4[0], acc[t][0]); m4[1] = fmaxf(m4[1], acc[t][1]);
    m4[2] = fmaxf(m4[2], acc[t][2]); m4[3] = fmaxf(m4[3], acc[t][3]);
  }
  float m = fmaxf(fmaxf(m4[0], m4[1]), fmaxf(m4[2], m4[3]));
  m = fmaxf(m, __shfl_xor(m, 16));
  m = fmaxf(m, __shfl_xor(m, 32));
  if (lq == 0) Rm[w][lr] = m;
  __syncthreads();
  m = fmaxf(fmaxf(Rm[0][lr], Rm[1][lr]), fmaxf(Rm[2][lr], Rm[3][lr]));

  // ---- exp in place; pass 2: sum + nonzero count ----
  f32x4 s4 = {0.f, 0.f, 0.f, 0.f}, c4 = {0.f, 0.f, 0.f, 0.f};
#pragma unroll
  for (int t = 0; t < 7; ++t) {
#pragma unroll
    for (int r = 0; r < 4; ++r) {
      const float e = __expf(acc[t][r] - m);
      acc[t][r] = e;
      s4[r] += e;
      if (e > 0.f) c4[r] += 1.f;
    }
  }
  float s = (s4[0] + s4[1]) + (s4[2] + s4[3]);
  float cnt = (c4[0] + c4[1]) + (c4[2] + c4[3]);
  s += __shfl_xor(s, 16); s += __shfl_xor(s, 32);
  cnt += __shfl_xor(cnt, 16); cnt += __shfl_xor(cnt, 32);
  if (lq == 0) { Rs[w][lr] = s; Rc[w][lr] = cnt; }
  __syncthreads();
  s = (Rs[0][lr] + Rs[1][lr]) + (Rs[2][lr] + Rs[3][lr]);
  cnt = (Rc[0][lr] + Rc[1][lr]) + (Rc[2][lr] + Rc[3][lr]);
  const float inv = 1.f / s;
  const float mean = 1.f / cnt;  // sum(p) == 1

  // ---- pass 3: variance of p over nonzeros ----
  f32x4 d4 = {0.f, 0.f, 0.f, 0.f};
#pragma unroll
  for (int t = 0; t < 7; ++t) {
#pragma unroll
    for (int r = 0; r < 4; ++r) {
      const float p = acc[t][r] * inv;
      const float dd = p - mean;
      if (acc[t][r] > 0.f) d4[r] += dd * dd;
    }
  }
  float dv = (d4[0] + d4[1]) + (d4[2] + d4[3]);
  dv += __shfl_xor(dv, 16); dv += __shfl_xor(dv, 32);
  if (lq == 0) Rv[w][lr] = dv;
  __syncthreads();
  dv = (Rv[0][lr] + Rv[1][lr]) + (Rv[2][lr] + Rv[3][lr]);
  const float thr = mean - 0.5f * sqrtf(dv / (cnt - 1.f));

  // ---- pass 4: survivor renormalizer (row max always survives: p_max >= mean >= thr) ----
  f32x4 t4 = {0.f, 0.f, 0.f, 0.f};
#pragma unroll
  for (int t = 0; t < 7; ++t) {
#pragma unroll
    for (int r = 0; r < 4; ++r) {
      if (!(acc[t][r] * inv < thr)) t4[r] += acc[t][r];
    }
  }
  float s2 = (t4[0] + t4[1]) + (t4[2] + t4[3]);
  s2 += __shfl_xor(s2, 16); s2 += __shfl_xor(s2, 32);
  if (lq == 0) R2[w][lr] = s2;
  __syncthreads();
  s2 = (R2[0][lr] + R2[1][lr]) + (R2[2][lr] + R2[3][lr]);
  const float inv2 = 1.f / s2;

  // ---- write P[q=lr][k] bf16 (wave w covers k in [w*112, w*112+112)) ----
#pragma unroll
  for (int t = 0; t < 7; ++t) {
#pragma unroll
    for (int rp = 0; rp < 4; rp += 2) {
      const float v0 = (acc[t][rp] * inv < thr) ? 0.f : acc[t][rp] * inv2;
      const float v1 = (acc[t][rp + 1] * inv < thr) ? 0.f : acc[t][rp + 1] * inv2;
      const unsigned int u = (unsigned int)f2bf(v0) | ((unsigned int)f2bf(v1) << 16);
      *(unsigned int*)&P[lr * PST + (w * 7 + t) * 16 + lq * 4 + rp] = u;
    }
  }
  __syncthreads();

  // phase 3: out^T[d][q] = V^T(64x448) . P(448x16). Wave w owns d-tile [w*16, w*16+16).
  f32x4 o = {0.f, 0.f, 0.f, 0.f};
#pragma unroll
  for (int c = 0; c < 14; ++c) {
    union { ushort4 hh[2]; bf16x8 v; } bf;
    bf.hh[0] = *(const ushort4*)&P[lr * PST + c * 32 + lq * 8];
    bf.hh[1] = *(const ushort4*)&P[lr * PST + c * 32 + lq * 8 + 4];
    const bf16x8 a = *(const bf16x8*)(vt_ + ((size_t)n * 64 + w * 16 + lr) * 448 + c * 32 + lq * 8);
    o = __builtin_amdgcn_mfma_f32_16x16x32_bf16(a, bf.v, o, 0, 0, 0);
  }

  // transpose 16x16 tile via wave-private LDS (no barrier: same-wave write->read)
#pragma unroll
  for (int r = 0; r < 4; ++r) OT[w][lq * 4 + r][lr] = o[r];
  const int qrow = lane >> 2, dg = lane & 3;
  ushort4 ov;
  ov.x = f2bf(OT[w][dg * 4 + 0][qrow]);
  ov.y = f2bf(OT[w][dg * 4 + 1][qrow]);
  ov.z = f2bf(OT[w][dg * 4 + 2][qrow]);
  ov.w = f2bf(OT[w][dg * 4 + 3][qrow]);
  *(ushort4*)(attn + ((size_t)(qt * 16 + qrow) * 16 + b) * 1024 + h * 64 + w * 16 + dg * 4) = ov;
}

// ---------------- launch ----------------
extern "C" void kernel_launch(void* const* d_in, const int* in_sizes, int n_in,
                              void* d_out, int out_size, void* d_ws, size_t ws_size,
                              hipStream_t stream) {
  (void)in_sizes; (void)n_in; (void)out_size; (void)ws_size;
  const float* x    = (const float*)d_in[0];
  const float* mem  = (const float*)d_in[1];
  const float* q_w  = (const float*)d_in[2];
  const float* q_b  = (const float*)d_in[3];
  const float* k_w  = (const float*)d_in[4];
  const float* k_b  = (const float*)d_in[5];
  const float* v_w  = (const float*)d_in[6];
  const float* v_b  = (const float*)d_in[7];
  const float* o_w  = (const float*)d_in[8];
  const float* o_b  = (const float*)d_in[9];
  const float* ln1w = (const float*)d_in[10];
  const float* ln1b = (const float*)d_in[11];
  const float* f1w  = (const float*)d_in[12];
  const float* f1b  = (const float*)d_in[13];
  const float* f2w  = (const float*)d_in[14];
  const float* f2b  = (const float*)d_in[15];
  const float* ln2w = (const float*)d_in[16];
  const float* ln2b = (const float*)d_in[17];

  unsigned short* WQ   = (unsigned short*)d_ws;        // 3x 1048576 contiguous = fused B
  unsigned short* WK   = WQ + 1048576;
  unsigned short* WV   = WK + 1048576;
  unsigned short* WO   = WV + 1048576;
  unsigned short* WF1  = WO + 1048576;                 // 4194304
  unsigned short* WF2  = WF1 + 4194304;                // 4194304
  unsigned short* ABUF = WF2 + 4194304;                // 7340032 (mem rows 0..1023, xn rows 1024..7167)
  unsigned short* QB   = ABUF + 7340032;               // 6291456 [n][384][64]; KB/VB at KOFF/VOFF
  unsigned short* KB   = QB + 6291456;                 // 7340032 [n][448][64]
  unsigned short* VB   = KB + 7340032;                 // 7340032 [n][448][64]
  unsigned short* VT   = VB + 7340032;                 // 7340032 [n][64][448]
  unsigned short* ATTN = VT + 7340032;                 // 6291456
  float*          X2   = (float*)(ATTN + 6291456);     // 6291456 f32
  float*          QKVB = (float*)ATTN;                 // 3072 f32, dead before attn writes ATTN
  unsigned short* XN2  = ATTN;                         // alias (attn dead after out-proj)
  unsigned short* HB   = ABUF;                         // alias (A/q/k/v staging dead after attention)

  // all weight/memory converts + bias concat in ONE launch
  cvt_all<<<13324, 256, 0, stream>>>(q_w, k_w, v_w, o_w, f1w, f2w, mem, q_b, k_b, v_b,
                                     WQ, WK, WV, WO, WF1, WF2, ABUF, QKVB);

  // LN1 -> xn (rows 1024.. of ABUF)
  ln_bf16<0><<<6144, 256, 0, stream>>>(x, ABUF + 1048576, ln1w, ln1b, nullptr, nullptr);

  // fused QKV: [mem;xn] x [Wq;Wk;Wv]^T, head-major epilogue. NBM=56 -> WM=7, NBN=24.
  gemm_bt<5, 128><<<1344, 256, 0, stream>>>(ABUF, WQ, QKVB, nullptr, QB, 7168, 3072, 1024, 1024, 1024, 24, 7);

  vtrans<<<dim3(7, 256), 256, 0, stream>>>(VB, VT);
  attn_kernel<<<6144, 256, 0, stream>>>(QB, KB, VT, ATTN);

  // out-proj + residual -> X2 (f32). BNT=64: grid 768 = 8 XCD x (6 m x 16 n).
  gemm_bt<2, 64><<<768, 256, 0, stream>>>(ATTN, WO, o_b, x, X2, 6144, 1024, 1024, 1024, 1024, 16, 6);

  // LN2 -> xn2, and prefill d_out = X2 + fc2_bias (fc2 accumulates into it)
  ln_bf16<1><<<6144, 256, 0, stream>>>(X2, XN2, ln2w, ln2b, f2b, (float*)d_out);

  // FFN.
  // fc1: BNT=128, grid 1536 = 8 XCD x (6 m x 32 n).
  gemm_bt<3, 128><<<1536, 256, 0, stream>>>(XN2, WF1, f1b, nullptr, HB, 6144, 4096, 1024, 1024, 1024, 32, 6);
  // fc2: BNT=128, split-K 2, grid 768 = 8 XCD x (6 m x 8 n x 2 kz), per-block K=2048;
  //      atomicAdd f32 into ln2-prefilled d_out.
  gemm_bt<6, 128><<<768, 256, 0, stream>>>(HB, WF2, nullptr, nullptr, d_out, 6144, 1024, 2048, 4096, 4096, 8, 6);
}

// Round 13
// 466.953 us; speedup vs baseline: 1.0911x; 1.0231x over previous
//
#include <hip/hip_runtime.h>

// ---------------- types / helpers ----------------
typedef __bf16 bf16x8 __attribute__((ext_vector_type(8)));
typedef float f32x4 __attribute__((ext_vector_type(4)));
typedef unsigned short u16x8 __attribute__((ext_vector_type(8)));

__device__ __forceinline__ unsigned short f2bf(float f) {
  union { float f; unsigned int u; } v; v.f = f;
  unsigned int r = v.u + 0x7fffu + ((v.u >> 16) & 1u);  // RNE
  return (unsigned short)(r >> 16);
}

__device__ __forceinline__ void async16(const unsigned short* g, unsigned short* l) {
  __builtin_amdgcn_global_load_lds(
      (const __attribute__((address_space(1))) unsigned int*)g,
      (__attribute__((address_space(3))) unsigned int*)l, 16, 0, 0);
}

// ---------------- fused converts: all weights + memory + bias concat, ONE launch ------
__global__ void cvt_all(const float* __restrict__ q_w, const float* __restrict__ k_w,
                        const float* __restrict__ v_w, const float* __restrict__ o_w,
                        const float* __restrict__ f1w, const float* __restrict__ f2w,
                        const float* __restrict__ mem,
                        const float* __restrict__ q_b, const float* __restrict__ k_b,
                        const float* __restrict__ v_b,
                        unsigned short* __restrict__ WQ, unsigned short* __restrict__ WK,
                        unsigned short* __restrict__ WV, unsigned short* __restrict__ WO,
                        unsigned short* __restrict__ WF1, unsigned short* __restrict__ WF2,
                        unsigned short* __restrict__ MEMB, float* __restrict__ QKVB) {
  const int bid = blockIdx.x;
  const float* src; unsigned short* dst; float scale = 1.f; int base;
  if (bid < 1024)       { src = q_w; dst = WQ;  scale = 0.125f; base = 0; }
  else if (bid < 2048)  { src = k_w; dst = WK;  base = 1024; }
  else if (bid < 3072)  { src = v_w; dst = WV;  base = 2048; }
  else if (bid < 4096)  { src = o_w; dst = WO;  base = 3072; }
  else if (bid < 8192)  { src = f1w; dst = WF1; base = 4096; }
  else if (bid < 12288) { src = f2w; dst = WF2; base = 8192; }
  else if (bid < 13312) { src = mem; dst = MEMB; base = 12288; }
  else {  // bias concat (12 blocks, 3072 elems), q-bias pre-scaled
    const int i = (bid - 13312) * 256 + threadIdx.x;
    QKVB[i] = (i < 1024) ? q_b[i] * 0.125f : (i < 2048 ? k_b[i - 1024] : v_b[i - 2048]);
    return;
  }
  const int i = (bid - base) * 256 + threadIdx.x;
  float4 v = ((const float4*)src)[i];
  ushort4 o;
  o.x = f2bf(v.x * scale); o.y = f2bf(v.y * scale);
  o.z = f2bf(v.z * scale); o.w = f2bf(v.w * scale);
  ((ushort4*)dst)[i] = o;
}

// ---------------- LayerNorm (per 1024-row) -> bf16 ----------------
template <int PREFILL>
__global__ __launch_bounds__(256) void ln_bf16(
    const float* __restrict__ src, unsigned short* __restrict__ dst,
    const float* __restrict__ g, const float* __restrict__ be,
    const float* __restrict__ fbias, float* __restrict__ dout) {
  const int row = blockIdx.x, tid = threadIdx.x;
  const float4 v = ((const float4*)(src + (size_t)row * 1024))[tid];
  if (PREFILL) {
    const float4 fb = ((const float4*)fbias)[tid];
    float4 r;
    r.x = v.x + fb.x; r.y = v.y + fb.y; r.z = v.z + fb.z; r.w = v.w + fb.w;
    ((float4*)(dout + (size_t)row * 1024))[tid] = r;
  }
  float s = v.x + v.y + v.z + v.w;
  float qq = v.x * v.x + v.y * v.y + v.z * v.z + v.w * v.w;
#pragma unroll
  for (int off = 32; off; off >>= 1) { s += __shfl_xor(s, off); qq += __shfl_xor(qq, off); }
  __shared__ float ps[4], pq[4];
  const int w = tid >> 6, lane = tid & 63;
  if (lane == 0) { ps[w] = s; pq[w] = qq; }
  __syncthreads();
  if (tid == 0) { ps[0] = ps[0] + ps[1] + ps[2] + ps[3]; pq[0] = pq[0] + pq[1] + pq[2] + pq[3]; }
  __syncthreads();
  const float mu = ps[0] * (1.f / 1024.f);
  const float var = pq[0] * (1.f / 1024.f) - mu * mu;
  const float rs = rsqrtf(var + 1e-5f);
  const float4 gv = ((const float4*)g)[tid];
  const float4 bv = ((const float4*)be)[tid];
  ushort4 o;
  o.x = f2bf((v.x - mu) * rs * gv.x + bv.x);
  o.y = f2bf((v.y - mu) * rs * gv.y + bv.y);
  o.z = f2bf((v.z - mu) * rs * gv.z + bv.z);
  o.w = f2bf((v.w - mu) * rs * gv.w + bv.w);
  ((ushort4*)(dst + (size_t)row * 1024))[tid] = o;
}

// ---------------- GEMM: C[M,N] = A[M,K] @ B[N,K]^T (+ bias), m97-style, BK=64 --------
// SESSION LEDGER (r1-12): deep-pipeline 1-blk/CU engines all fail (latency-bound);
// 256-thr kernel at 3-6 blk/CU wins via m114 implicit wave overlap. r10: LESS work
// per barrier = worse. r12: MORE work per barrier (BK=64, 2x16 MFMA per barrier
// pair, kiters halved) = -24us total; all GEMMs now < 102us.
// Per-op optima: fc1 BNT=128@1536; fc2 BNT=128 splitK2@768; outproj BNT=64@768.
// (256,4): reg cap 128 — no spill ((256,8) scratch catastrophe, r2).
#define KOFF 6291456ull
#define VOFF 13631488ull
template <int EPI, int BNT>
__global__ __launch_bounds__(256, 4) void gemm_bt(
    const unsigned short* __restrict__ A, const unsigned short* __restrict__ Bw,
    const float* __restrict__ bias, const float* __restrict__ resid,
    void* __restrict__ Cout, int M, int N, int K, int lda, int ldb, int NBN, int WM) {
  constexpr int NJ = BNT / 32;       // B-frags per wave; wave covers 16*NJ cols
  constexpr int BS = BNT * 32;       // u16 per B slab
  __shared__ __align__(16) unsigned short lA[2 * 128 * 32];  // [slab][128][32]
  __shared__ __align__(16) unsigned short lB[2 * BS];        // [slab][BNT][32]
  const int tid = threadIdx.x;
  const int w = tid >> 6, lane = tid & 63;
  const int lr = lane & 15, lq = lane >> 4;
  const int l = blockIdx.x;
  const int xcd = l & 7, r = l >> 3;
  const int bm = xcd * WM + (r % WM);
  const int rest = r / WM;
  const int bn = rest % NBN;
  const size_t koff = (size_t)(rest / NBN) * K;  // split-K offset (K = per-block K)
  const unsigned short* Ab = A + (size_t)bm * 128 * lda + koff;
  const unsigned short* Bb = Bw + (size_t)bn * BNT * ldb + koff;
  const int wm = (w & 1) << 6;
  const int wn = (w >> 1) * (16 * NJ);
  f32x4 acc[4][NJ] = {};
  const int kiters = K >> 6;         // BK=64
  const int c0 = tid, c1 = 256 + tid;
  const int r0 = c0 >> 2, o0 = (c0 & 3) << 3;
  const int r1 = c1 >> 2, o1 = (c1 & 3) << 3;
  for (int kt = 0; kt < kiters; ++kt) {
    const int kb = kt << 6;
    __syncthreads();
#pragma unroll
    for (int s = 0; s < 2; ++s) {
      const int kc = kb + s * 32;
      async16(Ab + (size_t)r0 * lda + kc + o0, lA + s * 4096 + c0 * 8);
      async16(Ab + (size_t)r1 * lda + kc + o1, lA + s * 4096 + c1 * 8);
      async16(Bb + (size_t)r0 * ldb + kc + o0, lB + s * BS + c0 * 8);
      if (BNT == 128) async16(Bb + (size_t)r1 * ldb + kc + o1, lB + s * BS + c1 * 8);
    }
    __syncthreads();
#pragma unroll
    for (int s = 0; s < 2; ++s) {
      bf16x8 af[4], bfr[NJ];
#pragma unroll
      for (int i = 0; i < 4; ++i)
        af[i] = *(const bf16x8*)(lA + s * 4096 + (wm + i * 16 + lr) * 32 + lq * 8);
#pragma unroll
      for (int j = 0; j < NJ; ++j)
        bfr[j] = *(const bf16x8*)(lB + s * BS + (wn + j * 16 + lr) * 32 + lq * 8);
#pragma unroll
      for (int i = 0; i < 4; ++i)
#pragma unroll
        for (int j = 0; j < NJ; ++j)
          acc[i][j] = __builtin_amdgcn_mfma_f32_16x16x32_bf16(af[i], bfr[j], acc[i][j], 0, 0, 0);
    }
  }
  const int which = (bn * BNT) >> 10;  // EPI5: 0=Q,1=K,2=V (block-uniform; 1024%BNT==0)
#pragma unroll
  for (int i = 0; i < 4; ++i) {
#pragma unroll
    for (int j = 0; j < NJ; ++j) {
      const int colg = bn * BNT + wn + j * 16 + lr;
      const float bi = (EPI == 6) ? 0.f : bias[colg];
      const int rowg0 = bm * 128 + wm + i * 16 + lq * 4;
#pragma unroll
      for (int r2 = 0; r2 < 4; ++r2) {
        const int rowg = rowg0 + r2;
        const float val = acc[i][j][r2] + bi;
        if (EPI == 5) {
          const int t = rowg >> 4, bb = rowg & 15;
          const int hh = (colg >> 6) & 15, dd = colg & 63;
          const size_t nn = (size_t)(bb * 16 + hh);
          unsigned short* q16 = (unsigned short*)Cout;
          if (which == 0) {
            if (rowg >= 1024) q16[(nn * 384 + (t - 64)) * 64 + dd] = f2bf(val);
          } else if (which == 1) {
            q16[KOFF + (nn * 448 + t) * 64 + dd] = f2bf(val);
          } else {
            q16[VOFF + (nn * 448 + t) * 64 + dd] = f2bf(val);
          }
        } else {
          const size_t idx = (size_t)rowg * N + colg;
          if (EPI == 2) ((float*)Cout)[idx] = val + resid[idx];
          else if (EPI == 3) ((unsigned short*)Cout)[idx] = f2bf(fmaxf(val, 0.f));
          else if (EPI == 6) atomicAdd(&((float*)Cout)[idx], acc[i][j][r2]);
        }
      }
    }
  }
}

// ---------------- V transpose: vb[n][t][d] -> vt[n][d][t] ----------------
__global__ __launch_bounds__(256) void vtrans(const unsigned short* __restrict__ vb,
                                              unsigned short* __restrict__ vt) {
  __shared__ __align__(16) unsigned short ls[64][80];
  const int kc = blockIdx.x, n = blockIdx.y;
  const int tid = threadIdx.x;
#pragma unroll
  for (int i = 0; i < 2; ++i) {
    const int c = i * 256 + tid;
    const int kk = c >> 3, dc = (c & 7) << 3;
    u16x8 val = *(const u16x8*)(vb + ((size_t)n * 448 + kc * 64 + kk) * 64 + dc);
    *(u16x8*)&ls[kk][dc] = val;
  }
  __syncthreads();
#pragma unroll
  for (int i = 0; i < 2; ++i) {
    const int c = i * 256 + tid;
    const int d = c >> 3, kx = (c & 7) << 3;
    u16x8 o;
#pragma unroll
    for (int j = 0; j < 8; ++j) o[j] = ls[kx + j][d];
    *(u16x8*)(vt + ((size_t)n * 64 + d) * 448 + kc * 64 + kx) = o;
  }
}

// ---------------- fused attention, S^T formulation, 4 waves/block ----------------
// ROUND 13: softmax pass reduction (attn was r12's top dispatch: 102us, VALUBusy 32%,
// MfmaUtil 4% — suppression-softmax arithmetic-bound).
//  (a) variance pass ELIMINATED via identity: since sum_nz(p)=1 and mean=1/cnt,
//      sum_nz((p-mean)^2) = sum(p^2) - 1/cnt = e2*inv^2 - mean, with e2 = sum(e^2)
//      accumulated in the exp pass (one FMA/elem). Removes a 28-elem pass, a
//      shuffle-reduce, an LDS round and a barrier. fmaxf(dv,0) guards f32
//      cancellation (old dv was always >= 0).
//  (b) survivor pass masks acc in place -> the P-write pass loses its 28 cmp+sel.
#define PST 468  // P row stride (u16): dword stride 234 == 10 mod 32 -> ~2-way (free)
__global__ __launch_bounds__(256) void attn_kernel(
    const unsigned short* __restrict__ qt_, const unsigned short* __restrict__ kt_,
    const unsigned short* __restrict__ vt_, unsigned short* __restrict__ attn) {
  __shared__ __align__(16) unsigned short P[16 * PST];  // 14976 B
  __shared__ float Rm[4][16], Rs[4][16], Rc[4][16], Rv[4][16], R2[4][16];
  __shared__ __align__(16) float OT[4][16][17];         // per-wave transpose buffers
  const int id = blockIdx.x;
  const int xcd = id & 7, j0 = id >> 3;
  const int n = xcd * 32 + (j0 & 31), qt = j0 >> 5;  // qt 0..23
  const int b = n >> 4, h = n & 15;
  const int tid = threadIdx.x, w = tid >> 6, lane = tid & 63;
  const int lr = lane & 15, lq = lane >> 4;

  const unsigned short* qp = qt_ + ((size_t)n * 384 + qt * 16 + lr) * 64 + lq * 8;
  const bf16x8 q0 = *(const bf16x8*)qp;
  const bf16x8 q1 = *(const bf16x8*)(qp + 32);

  // phase 1: S^T for 7 k-tiles. acc[t][r] = S[q=lr][k = (w*7+t)*16 + 4*lq + r]
  f32x4 acc[7];
#pragma unroll
  for (int t = 0; t < 7; ++t) {
    const unsigned short* kp = kt_ + ((size_t)n * 448 + (w * 7 + t) * 16 + lr) * 64 + lq * 8;
    const bf16x8 k0 = *(const bf16x8*)kp;
    const bf16x8 k1 = *(const bf16x8*)(kp + 32);
    f32x4 a = {0.f, 0.f, 0.f, 0.f};
    a = __builtin_amdgcn_mfma_f32_16x16x32_bf16(k0, q0, a, 0, 0, 0);
    a = __builtin_amdgcn_mfma_f32_16x16x32_bf16(k1, q1, a, 0, 0, 0);
    acc[t] = a;
  }

  // ---- pass 1: row max ----
  f32x4 m4 = acc[0];
#pragma unroll
  for (int t = 1; t < 7; ++t) {
    m4[0] = fmaxf(m4[0], acc[t][0]); m4[1] = fmaxf(m4[1], acc[t][1]);
    m4[2] = fmaxf(m4[2], acc[t][2]); m4[3] = fmaxf(m4[3], acc[t][3]);
  }
  float m = fmaxf(fmaxf(m4[0], m4[1]), fmaxf(m4[2], m4[3]));
  m = fmaxf(m, __shfl_xor(m, 16));
  m = fmaxf(m, __shfl_xor(m, 32));
  if (lq == 0) Rm[w][lr] = m;
  __syncthreads();
  m = fmaxf(fmaxf(Rm[0][lr], Rm[1][lr]), fmaxf(Rm[2][lr], Rm[3][lr]));

  // ---- pass 2: exp in place; sum + nonzero count + sum of squares ----
  f32x4 s4 = {0.f, 0.f, 0.f, 0.f}, c4 = {0.f, 0.f, 0.f, 0.f}, q4 = {0.f, 0.f, 0.f, 0.f};
#pragma unroll
  for (int t = 0; t < 7; ++t) {
#pragma unroll
    for (int r = 0; r < 4; ++r) {
      const float e = __expf(acc[t][r] - m);
      acc[t][r] = e;
      s4[r] += e;
      q4[r] = fmaf(e, e, q4[r]);
      if (e > 0.f) c4[r] += 1.f;
    }
  }
  float s = (s4[0] + s4[1]) + (s4[2] + s4[3]);
  float cnt = (c4[0] + c4[1]) + (c4[2] + c4[3]);
  float e2 = (q4[0] + q4[1]) + (q4[2] + q4[3]);
  s += __shfl_xor(s, 16); s += __shfl_xor(s, 32);
  cnt += __shfl_xor(cnt, 16); cnt += __shfl_xor(cnt, 32);
  e2 += __shfl_xor(e2, 16); e2 += __shfl_xor(e2, 32);
  if (lq == 0) { Rs[w][lr] = s; Rc[w][lr] = cnt; Rv[w][lr] = e2; }
  __syncthreads();
  s = (Rs[0][lr] + Rs[1][lr]) + (Rs[2][lr] + Rs[3][lr]);
  cnt = (Rc[0][lr] + Rc[1][lr]) + (Rc[2][lr] + Rc[3][lr]);
  e2 = (Rv[0][lr] + Rv[1][lr]) + (Rv[2][lr] + Rv[3][lr]);
  const float inv = 1.f / s;
  const float mean = 1.f / cnt;  // sum_nz(p) == 1
  // variance identity: sum_nz((p-mean)^2) = sum(p^2) - 1/cnt
  const float dvs = fmaxf(e2 * inv * inv - mean, 0.f);
  const float thr = mean - 0.5f * sqrtf(dvs / (cnt - 1.f));

  // ---- pass 3: mask survivors in place + survivor renormalizer ----
  // (row max always survives: p_max >= mean >= thr)
  f32x4 t4 = {0.f, 0.f, 0.f, 0.f};
#pragma unroll
  for (int t = 0; t < 7; ++t) {
#pragma unroll
    for (int r = 0; r < 4; ++r) {
      if (acc[t][r] * inv < thr) acc[t][r] = 0.f;
      t4[r] += acc[t][r];
    }
  }
  float s2 = (t4[0] + t4[1]) + (t4[2] + t4[3]);
  s2 += __shfl_xor(s2, 16); s2 += __shfl_xor(s2, 32);
  if (lq == 0) R2[w][lr] = s2;
  __syncthreads();
  s2 = (R2[0][lr] + R2[1][lr]) + (R2[2][lr] + R2[3][lr]);
  const float inv2 = 1.f / s2;

  // ---- write P[q=lr][k] bf16 (wave w covers k in [w*112, w*112+112)) ----
#pragma unroll
  for (int t = 0; t < 7; ++t) {
#pragma unroll
    for (int rp = 0; rp < 4; rp += 2) {
      const float v0 = acc[t][rp] * inv2;
      const float v1 = acc[t][rp + 1] * inv2;
      const unsigned int u = (unsigned int)f2bf(v0) | ((unsigned int)f2bf(v1) << 16);
      *(unsigned int*)&P[lr * PST + (w * 7 + t) * 16 + lq * 4 + rp] = u;
    }
  }
  __syncthreads();

  // phase 3: out^T[d][q] = V^T(64x448) . P(448x16). Wave w owns d-tile [w*16, w*16+16).
  f32x4 o = {0.f, 0.f, 0.f, 0.f};
#pragma unroll
  for (int c = 0; c < 14; ++c) {
    union { ushort4 hh[2]; bf16x8 v; } bf;
    bf.hh[0] = *(const ushort4*)&P[lr * PST + c * 32 + lq * 8];
    bf.hh[1] = *(const ushort4*)&P[lr * PST + c * 32 + lq * 8 + 4];
    const bf16x8 a = *(const bf16x8*)(vt_ + ((size_t)n * 64 + w * 16 + lr) * 448 + c * 32 + lq * 8);
    o = __builtin_amdgcn_mfma_f32_16x16x32_bf16(a, bf.v, o, 0, 0, 0);
  }

  // transpose 16x16 tile via wave-private LDS (no barrier: same-wave write->read)
#pragma unroll
  for (int r = 0; r < 4; ++r) OT[w][lq * 4 + r][lr] = o[r];
  const int qrow = lane >> 2, dg = lane & 3;
  ushort4 ov;
  ov.x = f2bf(OT[w][dg * 4 + 0][qrow]);
  ov.y = f2bf(OT[w][dg * 4 + 1][qrow]);
  ov.z = f2bf(OT[w][dg * 4 + 2][qrow]);
  ov.w = f2bf(OT[w][dg * 4 + 3][qrow]);
  *(ushort4*)(attn + ((size_t)(qt * 16 + qrow) * 16 + b) * 1024 + h * 64 + w * 16 + dg * 4) = ov;
}

// ---------------- launch ----------------
extern "C" void kernel_launch(void* const* d_in, const int* in_sizes, int n_in,
                              void* d_out, int out_size, void* d_ws, size_t ws_size,
                              hipStream_t stream) {
  (void)in_sizes; (void)n_in; (void)out_size; (void)ws_size;
  const float* x    = (const float*)d_in[0];
  const float* mem  = (const float*)d_in[1];
  const float* q_w  = (const float*)d_in[2];
  const float* q_b  = (const float*)d_in[3];
  const float* k_w  = (const float*)d_in[4];
  const float* k_b  = (const float*)d_in[5];
  const float* v_w  = (const float*)d_in[6];
  const float* v_b  = (const float*)d_in[7];
  const float* o_w  = (const float*)d_in[8];
  const float* o_b  = (const float*)d_in[9];
  const float* ln1w = (const float*)d_in[10];
  const float* ln1b = (const float*)d_in[11];
  const float* f1w  = (const float*)d_in[12];
  const float* f1b  = (const float*)d_in[13];
  const float* f2w  = (const float*)d_in[14];
  const float* f2b  = (const float*)d_in[15];
  const float* ln2w = (const float*)d_in[16];
  const float* ln2b = (const float*)d_in[17];

  unsigned short* WQ   = (unsigned short*)d_ws;        // 3x 1048576 contiguous = fused B
  unsigned short* WK   = WQ + 1048576;
  unsigned short* WV   = WK + 1048576;
  unsigned short* WO   = WV + 1048576;
  unsigned short* WF1  = WO + 1048576;                 // 4194304
  unsigned short* WF2  = WF1 + 4194304;                // 4194304
  unsigned short* ABUF = WF2 + 4194304;                // 7340032 (mem rows 0..1023, xn rows 1024..7167)
  unsigned short* QB   = ABUF + 7340032;               // 6291456 [n][384][64]; KB/VB at KOFF/VOFF
  unsigned short* KB   = QB + 6291456;                 // 7340032 [n][448][64]
  unsigned short* VB   = KB + 7340032;                 // 7340032 [n][448][64]
  unsigned short* VT   = VB + 7340032;                 // 7340032 [n][64][448]
  unsigned short* ATTN = VT + 7340032;                 // 6291456
  float*          X2   = (float*)(ATTN + 6291456);     // 6291456 f32
  float*          QKVB = (float*)ATTN;                 // 3072 f32, dead before attn writes ATTN
  unsigned short* XN2  = ATTN;                         // alias (attn dead after out-proj)
  unsigned short* HB   = ABUF;                         // alias (A/q/k/v staging dead after attention)

  // all weight/memory converts + bias concat in ONE launch
  cvt_all<<<13324, 256, 0, stream>>>(q_w, k_w, v_w, o_w, f1w, f2w, mem, q_b, k_b, v_b,
                                     WQ, WK, WV, WO, WF1, WF2, ABUF, QKVB);

  // LN1 -> xn (rows 1024.. of ABUF)
  ln_bf16<0><<<6144, 256, 0, stream>>>(x, ABUF + 1048576, ln1w, ln1b, nullptr, nullptr);

  // fused QKV: [mem;xn] x [Wq;Wk;Wv]^T, head-major epilogue. NBM=56 -> WM=7, NBN=24.
  gemm_bt<5, 128><<<1344, 256, 0, stream>>>(ABUF, WQ, QKVB, nullptr, QB, 7168, 3072, 1024, 1024, 1024, 24, 7);

  vtrans<<<dim3(7, 256), 256, 0, stream>>>(VB, VT);
  attn_kernel<<<6144, 256, 0, stream>>>(QB, KB, VT, ATTN);

  // out-proj + residual -> X2 (f32). BNT=64: grid 768 = 8 XCD x (6 m x 16 n).
  gemm_bt<2, 64><<<768, 256, 0, stream>>>(ATTN, WO, o_b, x, X2, 6144, 1024, 1024, 1024, 1024, 16, 6);

  // LN2 -> xn2, and prefill d_out = X2 + fc2_bias (fc2 accumulates into it)
  ln_bf16<1><<<6144, 256, 0, stream>>>(X2, XN2, ln2w, ln2b, f2b, (float*)d_out);

  // FFN.
  // fc1: BNT=128, grid 1536 = 8 XCD x (6 m x 32 n).
  gemm_bt<3, 128><<<1536, 256, 0, stream>>>(XN2, WF1, f1b, nullptr, HB, 6144, 4096, 1024, 1024, 1024, 32, 6);
  // fc2: BNT=128, split-K 2, grid 768 = 8 XCD x (6 m x 8 n x 2 kz), per-block K=2048;
  //      atomicAdd f32 into ln2-prefilled d_out.
  gemm_bt<6, 128><<<768, 256, 0, stream>>>(HB, WF2, nullptr, nullptr, d_out, 6144, 1024, 2048, 4096, 4096, 8, 6);
}